// Round 22
// baseline (85.195 us; speedup 1.0000x reference)
//
#include <hip/hip_runtime.h>
#include <hip/hip_bf16.h>

#define C_DIM 512
#define L_DIM 1024
#define KK 64
#define KG 65
#define KP 80   // padded k rows (5 tiles of 16)

using f32x4  = __attribute__((ext_vector_type(4))) float;
using bf16x8 = __attribute__((ext_vector_type(8))) short;

union U4 { uint4 u; bf16x8 b; };

__device__ __forceinline__ unsigned bfh(float x) { return __float_as_uint(x) >> 16; }
__device__ __forceinline__ float bfh_f(float x) { return __uint_as_float(__float_as_uint(x) & 0xFFFF0000u); }

// pack two fp32 -> word of 2 bf16 (truncation): low16 = a, high16 = b
__device__ __forceinline__ unsigned pack2(float a, float b) {
    return __builtin_amdgcn_perm(__float_as_uint(b), __float_as_uint(a), 0x07060302u);
}

// async global->LDS DMA, 16 B/lane (wave covers 1 KB: LDS dest = base + lane*16)
__device__ __forceinline__ void load_lds16(const void* g, void* l) {
    __builtin_amdgcn_global_load_lds(
        (const __attribute__((address_space(1))) void*)g,
        (__attribute__((address_space(3))) void*)l, 16, 0, 0);
}

// ---------------- prep: conv_w split bf16 hi/lo, MFMA fragment order, merged buffer --
__global__ void k_prep(const float* __restrict__ conv_w, const float* __restrict__ conv_b,
                       unsigned short* __restrict__ wp, float* __restrict__ wb)
{
    int ch = blockIdx.x;          // 0..15
    int kt = blockIdx.y;          // 0..4
    int t  = threadIdx.x;         // 0..255
    for (int p = 0; p < 2; ++p) {
        int idx = p * 256 + t;    // 0..511
        int lane = idx >> 3, j = idx & 7;
        int k = kt * 16 + (lane & 15);
        int c = ch * 32 + (lane >> 4) * 8 + j;
        float v = (k < KG) ? conv_w[k * C_DIM + c] : 0.f;
        unsigned h = bfh(v);
        float r = v - __uint_as_float(h << 16);
        wp[((ch * 10 + kt) << 9) + idx]     = (unsigned short)h;
        wp[((ch * 10 + 5 + kt) << 9) + idx] = (unsigned short)bfh(r);
    }
    if (ch == 0 && kt == 0 && t < KP) wb[t] = (t < KG) ? conv_b[t] : -1e30f;
}

// ---------------- Stage 1: fully DMA-staged, 3-chunk-deep COUNTED-vmcnt pipeline -----
// Grid (8 lb, 64 n), block 256 = 4 waves. Per chunk & wave: x 4 DMAs + weights 2-3.
// 3-buffer rotation: during compute of chunk i, chunks i+1 AND i+2 are in flight
// (two compute phases to cover ~900cy HBM latency). Steady-state waits vmcnt(14/12);
// tail drains 7/6 -> 0. LDS 78.75 KB -> still 2 blocks/CU.
#define XSEG 260   // floats per 1 KB x-segment + 16 B pad
__global__ __launch_bounds__(256) void k_s1(
    const float* __restrict__ x, const unsigned short* __restrict__ wp,
    const float* __restrict__ wb,
    unsigned* __restrict__ aPh32, unsigned* __restrict__ aPl32,
    float* __restrict__ asum_part)
{
    __shared__ float xs[3][16 * XSEG];              // 3 x 16.25 KB
    __shared__ unsigned short wlds[3][10 << 9];     // 3 x 10 KB

    const int lb = blockIdx.x, n = blockIdx.y;
    const int t = threadIdx.x, lane = t & 63, w = t >> 6;
    const int arow = lane & 15;          // A/C row & B col within tile
    const int agrp = lane >> 4;          // k-slice group
    const int gl0 = lb * 128;            // block's global l base
    const int lw0 = gl0 + w * 32;        // wave's global l base
    const int choff = (lb + n) & 15;     // block-uniform chunk rotation

    const float* xbase = x + (size_t)n * C_DIM * L_DIM;

    // x: wave w stages segments s = w*4..w*4+3 (seg s = c-rows {ch*32+2s, +1})
#define XSTAGE(b, ch) { _Pragma("unroll") \
    for (int i = 0; i < 4; ++i) { \
        int s = w * 4 + i; \
        const float* src = &xbase[(size_t)((ch) * 32 + s * 2 + (lane >> 5)) * L_DIM \
                                  + gl0 + (lane & 31) * 4]; \
        load_lds16(src, &xs[b][s * XSEG]); \
    } }
    // weights: wave w stages segs {w, w+4}; waves 0,1 also {8,9}
#define WSTAGE(b, ch) { \
    load_lds16(&wp[(((ch) * 10 + w) << 9) + (lane << 3)], &wlds[b][w << 9]); \
    load_lds16(&wp[(((ch) * 10 + w + 4) << 9) + (lane << 3)], &wlds[b][(w + 4) << 9]); \
    if (w < 2) \
        load_lds16(&wp[(((ch) * 10 + 8 + w) << 9) + (lane << 3)], &wlds[b][(8 + w) << 9]); \
    }

    f32x4 acc[5][2];
#pragma unroll
    for (int a = 0; a < 5; ++a)
#pragma unroll
        for (int b = 0; b < 2; ++b) acc[a][b] = (f32x4)0.f;
    float ss0 = 0.f, ss1 = 0.f;

    // prologue: stage chunks 0,1,2 into the three buffers (7/6 DMAs per wave each)
    XSTAGE(0, choff) WSTAGE(0, choff)
    XSTAGE(1, (1 + choff) & 15) WSTAGE(1, (1 + choff) & 15)
    XSTAGE(2, (2 + choff) & 15) WSTAGE(2, (2 + choff) & 15)

#pragma unroll 3
    for (int ch0 = 0; ch0 < 16; ++ch0) {
        const int cur = ch0 % 3;
        // counted wait: own current-chunk DMAs done; deeper chunks stay in flight
        if (ch0 == 15)      { asm volatile("s_waitcnt vmcnt(0)" ::: "memory"); }
        else if (ch0 == 14) {
            if (w < 2) { asm volatile("s_waitcnt vmcnt(7)" ::: "memory"); }
            else       { asm volatile("s_waitcnt vmcnt(6)" ::: "memory"); }
        } else {
            if (w < 2) { asm volatile("s_waitcnt vmcnt(14)" ::: "memory"); }
            else       { asm volatile("s_waitcnt vmcnt(12)" ::: "memory"); }
        }
        __builtin_amdgcn_s_barrier();          // all waves' cur data visible
        __builtin_amdgcn_sched_barrier(0);     // rule #18: no hoisting past the wait
        // ---- x fragments from LDS (one float2 feeds both l-tiles)
        float e0[8], e1[8];
#pragma unroll
        for (int j = 0; j < 8; ++j) {
            int c = agrp * 8 + j;
            float2 v = *reinterpret_cast<const float2*>(
                &xs[cur][(c >> 1) * XSEG + (c & 1) * 128 + w * 32 + 2 * arow]);
            e0[j] = v.x;     // l = lw0 + 2*arow     (tile 0)
            e1[j] = v.y;     // l = lw0 + 2*arow + 1 (tile 1)
        }
#pragma unroll
        for (int j = 0; j < 8; ++j) { ss0 += e0[j] * e0[j]; ss1 += e1[j] * e1[j]; }
        U4 bh[2], bl[2];
        bh[0].u.x = pack2(e0[0], e0[1]); bh[0].u.y = pack2(e0[2], e0[3]);
        bh[0].u.z = pack2(e0[4], e0[5]); bh[0].u.w = pack2(e0[6], e0[7]);
        bh[1].u.x = pack2(e1[0], e1[1]); bh[1].u.y = pack2(e1[2], e1[3]);
        bh[1].u.z = pack2(e1[4], e1[5]); bh[1].u.w = pack2(e1[6], e1[7]);
        float r0, r1, r2, r3;
        r0 = e0[0] - bfh_f(e0[0]); r1 = e0[1] - bfh_f(e0[1]);
        r2 = e0[2] - bfh_f(e0[2]); r3 = e0[3] - bfh_f(e0[3]);
        bl[0].u.x = pack2(r0, r1); bl[0].u.y = pack2(r2, r3);
        r0 = e0[4] - bfh_f(e0[4]); r1 = e0[5] - bfh_f(e0[5]);
        r2 = e0[6] - bfh_f(e0[6]); r3 = e0[7] - bfh_f(e0[7]);
        bl[0].u.z = pack2(r0, r1); bl[0].u.w = pack2(r2, r3);
        r0 = e1[0] - bfh_f(e1[0]); r1 = e1[1] - bfh_f(e1[1]);
        r2 = e1[2] - bfh_f(e1[2]); r3 = e1[3] - bfh_f(e1[3]);
        bl[1].u.x = pack2(r0, r1); bl[1].u.y = pack2(r2, r3);
        r0 = e1[4] - bfh_f(e1[4]); r1 = e1[5] - bfh_f(e1[5]);
        r2 = e1[6] - bfh_f(e1[6]); r3 = e1[7] - bfh_f(e1[7]);
        bl[1].u.z = pack2(r0, r1); bl[1].u.w = pack2(r2, r3);
        // ---- weight fragments from LDS (broadcast across waves)
        U4 ah[5], al[5];
#pragma unroll
        for (int kt = 0; kt < 5; ++kt) {
            ah[kt].u = *reinterpret_cast<const uint4*>(&wlds[cur][(kt << 9) + (lane << 3)]);
            al[kt].u = *reinterpret_cast<const uint4*>(&wlds[cur][((5 + kt) << 9) + (lane << 3)]);
        }
#pragma unroll
        for (int kt = 0; kt < 5; ++kt)
#pragma unroll
            for (int lt = 0; lt < 2; ++lt) {
                acc[kt][lt] = __builtin_amdgcn_mfma_f32_16x16x32_bf16(ah[kt].b, bh[lt].b, acc[kt][lt], 0, 0, 0);
                acc[kt][lt] = __builtin_amdgcn_mfma_f32_16x16x32_bf16(ah[kt].b, bl[lt].b, acc[kt][lt], 0, 0, 0);
                acc[kt][lt] = __builtin_amdgcn_mfma_f32_16x16x32_bf16(al[kt].b, bh[lt].b, acc[kt][lt], 0, 0, 0);
            }
        __builtin_amdgcn_s_barrier();          // all waves done reading buf cur
        if (ch0 < 13) {
            const int nx = (ch0 + 3 + choff) & 15;
            XSTAGE(cur, nx) WSTAGE(cur, nx)    // refill freed buffer, stays in flight
        }
    }

    ss0 += __shfl_xor(ss0, 16, 64); ss0 += __shfl_xor(ss0, 32, 64);
    ss1 += __shfl_xor(ss1, 16, 64); ss1 += __shfl_xor(ss1, 32, 64);
    float invc[2];
    invc[0] = 1.0f / fmaxf(sqrtf(ss0), 1e-12f);
    invc[1] = 1.0f / fmaxf(sqrtf(ss1), 1e-12f);

    float4 wbv[5];
#pragma unroll
    for (int kt = 0; kt < 5; ++kt)
        wbv[kt] = *reinterpret_cast<const float4*>(&wb[kt * 16 + agrp * 4]);

    float aval[5][2][4];
    float rs[2];
#pragma unroll
    for (int lt = 0; lt < 2; ++lt) {
        float m = -1e30f;
#pragma unroll
        for (int kt = 0; kt < 5; ++kt)
#pragma unroll
            for (int r = 0; r < 4; ++r) {
                float lg = acc[kt][lt][r] * invc[lt] + ((const float*)&wbv[kt])[r];
                aval[kt][lt][r] = lg;
                m = fmaxf(m, lg);
            }
        m = fmaxf(m, __shfl_xor(m, 16, 64));
        m = fmaxf(m, __shfl_xor(m, 32, 64));
        float s = 0.f;
#pragma unroll
        for (int kt = 0; kt < 5; ++kt)
#pragma unroll
            for (int r = 0; r < 4; ++r) {
                float e = __expf(aval[kt][lt][r] - m);
                aval[kt][lt][r] = e;
                s += e;
            }
        s += __shfl_xor(s, 16, 64);
        s += __shfl_xor(s, 32, 64);
        rs[lt] = 1.0f / s;
    }

#pragma unroll
    for (int kt = 0; kt < 4; ++kt)
#pragma unroll
        for (int r = 0; r < 4; ++r) {
            int k = kt * 16 + agrp * 4 + r;
            float s01 = 0.f;
#pragma unroll
            for (int lt = 0; lt < 2; ++lt) {
                float a = aval[kt][lt][r] * rs[lt];
                aval[kt][lt][r] = a;
                s01 += a;
            }
#pragma unroll
            for (int off = 8; off; off >>= 1) s01 += __shfl_xor(s01, off, 64);
            if ((lane & 15) == 0)
                asum_part[((n * 8 + lb) * 4 + w) * KK + k] = s01;
            // packed u32 stores: both adjacent l's in one word (dense 64 B segments)
            float ap0 = aval[kt][0][r] * invc[0];
            float ap1 = aval[kt][1][r] * invc[1];
            unsigned h0 = bfh(ap0), h1 = bfh(ap1);
            float q0 = ap0 - __uint_as_float(h0 << 16);
            float q1 = ap1 - __uint_as_float(h1 << 16);
            int widx = (n * KK + k) * (L_DIM / 2) + (lw0 >> 1) + arow;
            aPh32[widx] = h0 | (h1 << 16);
            aPl32[widx] = bfh(q0) | (bfh(q1) << 16);
        }
}

// ---------------- a_sum reduce ----------------
__global__ void k_asum(const float* __restrict__ part, float* __restrict__ a_sum)
{
    int id = blockIdx.x * 256 + threadIdx.x;  // 4096
    int n = id >> 6, k = id & 63;
    float s = 0.f;
#pragma unroll
    for (int p = 0; p < 32; ++p) s += part[(n * 32 + p) * KK + k];
    a_sum[id] = s;
}

// ---------------- Stage 2: vlad = a'x^T - a_sum*cent, fused rnpart, XCD swizzle ------
#define S2P 72   // LDS row pitch in shorts (144 B, 16B-aligned rows)
__global__ __launch_bounds__(256) void k_s2v(
    const float* __restrict__ x, const unsigned short* __restrict__ aPh,
    const unsigned short* __restrict__ aPl, const float* __restrict__ a_sum,
    const float* __restrict__ cent, float* __restrict__ vlad,
    float* __restrict__ rnpart)
{
    __shared__ unsigned short Ah[64 * S2P], Al[64 * S2P];   // aP chunk [k][l]
    __shared__ unsigned short Bh[64 * S2P], Bl[64 * S2P];   // x  chunk [c][l]
    __shared__ float rnbuf[4][64];

    const int flat = blockIdx.x;
    const int cq = flat >> 6;                               // 0..7
    const int n  = ((flat & 7) << 3) | ((flat >> 3) & 7);   // bijective, XCD-pinned
    const int t = threadIdx.x, lane = t & 63, w = t >> 6;
    const int arow = lane & 15, agrp = lane >> 4;

    f32x4 acc[4];
#pragma unroll
    for (int a = 0; a < 4; ++a) acc[a] = (f32x4)0.f;

    for (int step = 0; step < 16; ++step) {
        const int l0 = step * 64;
        __syncthreads();   // previous iter's reads done before restage
#pragma unroll
        for (int p = 0; p < 2; ++p) {
            int idx = p * 256 + t;          // 0..511 (512 uint4 = 4096 shorts)
            int k = idx >> 3;               // 8 uint4 per 64-short row
            int lc = (idx & 7) * 8;
            size_t g = (size_t)(n * KK + k) * L_DIM + l0 + lc;
            *reinterpret_cast<uint4*>(&Ah[k * S2P + lc]) = *reinterpret_cast<const uint4*>(&aPh[g]);
            *reinterpret_cast<uint4*>(&Al[k * S2P + lc]) = *reinterpret_cast<const uint4*>(&aPl[g]);
        }
#pragma unroll
        for (int p = 0; p < 4; ++p) {
            int idx = p * 256 + t;          // 0..1023 (1024 float4)
            int c = idx >> 4;               // 16 float4 per 64-float row
            int lc = (idx & 15) * 4;
            float4 v = *reinterpret_cast<const float4*>(
                &x[((size_t)n * C_DIM + cq * 64 + c) * L_DIM + l0 + lc]);
            uint2 hw, lw;
            hw.x = pack2(v.x, v.y); hw.y = pack2(v.z, v.w);
            float r0 = v.x - bfh_f(v.x), r1 = v.y - bfh_f(v.y);
            float r2 = v.z - bfh_f(v.z), r3 = v.w - bfh_f(v.w);
            lw.x = pack2(r0, r1); lw.y = pack2(r2, r3);
            *reinterpret_cast<uint2*>(&Bh[c * S2P + lc]) = hw;
            *reinterpret_cast<uint2*>(&Bl[c * S2P + lc]) = lw;
        }
        __syncthreads();
#pragma unroll
        for (int ks = 0; ks < 2; ++ks) {
            const int koff = ks * 32 + agrp * 8;
            U4 bh, bl;
            bh.u = *reinterpret_cast<const uint4*>(&Bh[(w * 16 + arow) * S2P + koff]);
            bl.u = *reinterpret_cast<const uint4*>(&Bl[(w * 16 + arow) * S2P + koff]);
#pragma unroll
            for (int kt = 0; kt < 4; ++kt) {
                U4 ah, al;
                ah.u = *reinterpret_cast<const uint4*>(&Ah[(kt * 16 + arow) * S2P + koff]);
                al.u = *reinterpret_cast<const uint4*>(&Al[(kt * 16 + arow) * S2P + koff]);
                acc[kt] = __builtin_amdgcn_mfma_f32_16x16x32_bf16(ah.b, bh.b, acc[kt], 0, 0, 0);
                acc[kt] = __builtin_amdgcn_mfma_f32_16x16x32_bf16(ah.b, bl.b, acc[kt], 0, 0, 0);
                acc[kt] = __builtin_amdgcn_mfma_f32_16x16x32_bf16(al.b, bh.b, acc[kt], 0, 0, 0);
            }
        }
    }
    // ---- fused epilogue: v = acc - a_sum*cent; store v; per-k sumsq partial
    const int c = cq * 64 + w * 16 + arow;
    float myrn[4][4];
#pragma unroll
    for (int kt = 0; kt < 4; ++kt)
#pragma unroll
        for (int r = 0; r < 4; ++r) {
            int k = kt * 16 + agrp * 4 + r;
            float as = a_sum[n * 64 + k];
            float cv = cent[k * C_DIM + c];
            float v = acc[kt][r] - as * cv;
            vlad[((size_t)n * KK + k) * C_DIM + c] = v;
            float sq = v * v;
            sq += __shfl_xor(sq, 1, 64);
            sq += __shfl_xor(sq, 2, 64);
            sq += __shfl_xor(sq, 4, 64);
            sq += __shfl_xor(sq, 8, 64);
            myrn[kt][r] = sq;               // valid at arow == 0
        }
    if (arow == 0) {
#pragma unroll
        for (int kt = 0; kt < 4; ++kt)
#pragma unroll
            for (int r = 0; r < 4; ++r)
                rnbuf[w][kt * 16 + agrp * 4 + r] = myrn[kt][r];
    }
    __syncthreads();
    if (t < 64) {
        float s = rnbuf[0][t] + rnbuf[1][t] + rnbuf[2][t] + rnbuf[3][t];
        rnpart[((size_t)n * 64 + t) * 8 + cq] = s;
    }
}

// ---------------- per-n scale from rnpart ----------------
__global__ void k_scale(const float* __restrict__ rnpart, float* __restrict__ scale)
{
    int n = blockIdx.x;
    int k = threadIdx.x;    // 64
    float s = 0.f;
#pragma unroll
    for (int q = 0; q < 8; ++q) s += rnpart[((size_t)n * 64 + k) * 8 + q];
    float nrm = sqrtf(s);
    float den = fmaxf(nrm, 1e-12f);
    float tk = nrm / den;
    float tot = tk * tk;
#pragma unroll
    for (int off = 32; off; off >>= 1) tot += __shfl_down(tot, off, 64);
    tot = __shfl(tot, 0, 64);
    float g = fmaxf(sqrtf(tot), 1e-12f);
    scale[n * 64 + k] = 1.0f / (den * g);
}

// ---------------- final output: v * scale ----------------
__global__ void k_out(const float* __restrict__ vlad, const float* __restrict__ scale,
                      float* __restrict__ out)
{
    int nk = blockIdx.x;
    int t = threadIdx.x;
    float sc = scale[nk];
    for (int c = t; c < C_DIM; c += 256)
        out[(size_t)nk * C_DIM + c] = vlad[(size_t)nk * C_DIM + c] * sc;
}

extern "C" void kernel_launch(void* const* d_in, const int* in_sizes, int n_in,
                              void* d_out, int out_size, void* d_ws, size_t ws_size,
                              hipStream_t stream)
{
    const float* x    = (const float*)d_in[0];
    const float* cent = (const float*)d_in[1];
    const float* cw   = (const float*)d_in[2];
    const float* cb   = (const float*)d_in[3];
    float* out = (float*)d_out;
    char* ws = (char*)d_ws;

    unsigned short* wp  = (unsigned short*)(ws + 0);                // 160 KB merged
    float*          wb  = (float*)(ws + 262144);                    // 320 B
    unsigned short* aPh = (unsigned short*)(ws + 524288);           // 8 MB
    unsigned short* aPl = (unsigned short*)(ws + 8912896);          // 8 MB
    float* asum_part    = (float*)(ws + 17301504);                  // 512 KB
    float* a_sum        = (float*)(ws + 17825792);                  // 16 KB
    float* vlad         = (float*)(ws + 18874368);                  // 8 MB
    float* rnpart       = (float*)(ws + 27262976);                  // 128 KB
    float* scale        = (float*)(ws + 27394048);                  // 16 KB

    k_prep<<<dim3(16, 5), 256, 0, stream>>>(cw, cb, wp, wb);
    k_s1<<<dim3(8, 64), 256, 0, stream>>>(x, wp, wb,
                                          (unsigned*)aPh, (unsigned*)aPl, asum_part);
    k_asum<<<16, 256, 0, stream>>>(asum_part, a_sum);
    k_s2v<<<512, 256, 0, stream>>>(x, aPh, aPl, a_sum, cent, vlad, rnpart);
    k_scale<<<64, 64, 0, stream>>>(rnpart, scale);
    k_out<<<4096, 256, 0, stream>>>(vlad, scale, out);
}

// Round 23
// 71.129 us; speedup vs baseline: 1.1978x; 1.1978x over previous
//
#include <hip/hip_runtime.h>
#include <hip/hip_bf16.h>

#define C_DIM 512
#define L_DIM 1024
#define KK 64
#define KG 65
#define KP 80   // padded k rows (5 tiles of 16)

using f32x4  = __attribute__((ext_vector_type(4))) float;
using bf16x8 = __attribute__((ext_vector_type(8))) short;

union U4 { uint4 u; bf16x8 b; };

__device__ __forceinline__ unsigned bfh(float x) { return __float_as_uint(x) >> 16; }
__device__ __forceinline__ float bfh_f(float x) { return __uint_as_float(__float_as_uint(x) & 0xFFFF0000u); }

// pack two fp32 -> word of 2 bf16 (truncation): low16 = a, high16 = b
__device__ __forceinline__ unsigned pack2(float a, float b) {
    return __builtin_amdgcn_perm(__float_as_uint(b), __float_as_uint(a), 0x07060302u);
}

// async global->LDS DMA, 16 B/lane (wave covers 1 KB: LDS dest = base + lane*16)
__device__ __forceinline__ void load_lds16(const void* g, void* l) {
    __builtin_amdgcn_global_load_lds(
        (const __attribute__((address_space(1))) void*)g,
        (__attribute__((address_space(3))) void*)l, 16, 0, 0);
}

// ---------------- prep: conv_w split bf16 hi/lo, MFMA fragment order, merged buffer --
__global__ void k_prep(const float* __restrict__ conv_w, const float* __restrict__ conv_b,
                       unsigned short* __restrict__ wp, float* __restrict__ wb)
{
    int ch = blockIdx.x;          // 0..15
    int kt = blockIdx.y;          // 0..4
    int t  = threadIdx.x;         // 0..255
    for (int p = 0; p < 2; ++p) {
        int idx = p * 256 + t;    // 0..511
        int lane = idx >> 3, j = idx & 7;
        int k = kt * 16 + (lane & 15);
        int c = ch * 32 + (lane >> 4) * 8 + j;
        float v = (k < KG) ? conv_w[k * C_DIM + c] : 0.f;
        unsigned h = bfh(v);
        float r = v - __uint_as_float(h << 16);
        wp[((ch * 10 + kt) << 9) + idx]     = (unsigned short)h;
        wp[((ch * 10 + 5 + kt) << 9) + idx] = (unsigned short)bfh(r);
    }
    if (ch == 0 && kt == 0 && t < KP) wb[t] = (t < KG) ? conv_b[t] : -1e30f;
}

// ---------------- Stage 1: fully DMA-staged, 2-chunk-deep COUNTED-vmcnt pipeline -----
// Grid (8 lb, 64 n), block 256 = 4 waves. Per chunk: x = 16 DMA segs (1 KB each,
// contiguous), weights = 10 DMA segs. Per-wave issue counts {7,7,6,6}; counted
// s_waitcnt vmcnt(own_next_count) + raw s_barrier keeps next chunk's 26 DMAs in
// flight across this chunk's compute (T3/T4 — never drain vmcnt(0) in the loop).
#define XSEG 260   // floats per 1 KB x-segment + 16 B pad
__global__ __launch_bounds__(256) void k_s1(
    const float* __restrict__ x, const unsigned short* __restrict__ wp,
    const float* __restrict__ wb,
    unsigned* __restrict__ aPh32, unsigned* __restrict__ aPl32,
    float* __restrict__ asum_part)
{
    __shared__ float xs[2][16 * XSEG];              // 2 x 16.25 KB
    __shared__ unsigned short wlds[2][10 << 9];     // 2 x 10 KB

    const int lb = blockIdx.x, n = blockIdx.y;
    const int t = threadIdx.x, lane = t & 63, w = t >> 6;
    const int arow = lane & 15;          // A/C row & B col within tile
    const int agrp = lane >> 4;          // k-slice group
    const int gl0 = lb * 128;            // block's global l base
    const int lw0 = gl0 + w * 32;        // wave's global l base
    const int choff = (lb + n) & 15;     // block-uniform chunk rotation

    const float* xbase = x + (size_t)n * C_DIM * L_DIM;

    // x: wave w stages segments s = w*4..w*4+3 (seg s = c-rows {ch*32+2s, +1})
#define XSTAGE(b, ch) { _Pragma("unroll") \
    for (int i = 0; i < 4; ++i) { \
        int s = w * 4 + i; \
        const float* src = &xbase[(size_t)((ch) * 32 + s * 2 + (lane >> 5)) * L_DIM \
                                  + gl0 + (lane & 31) * 4]; \
        load_lds16(src, &xs[b][s * XSEG]); \
    } }
    // weights: wave w stages segs {w, w+4}; waves 0,1 also {8,9}
#define WSTAGE(b, ch) { \
    load_lds16(&wp[(((ch) * 10 + w) << 9) + (lane << 3)], &wlds[b][w << 9]); \
    load_lds16(&wp[(((ch) * 10 + w + 4) << 9) + (lane << 3)], &wlds[b][(w + 4) << 9]); \
    if (w < 2) \
        load_lds16(&wp[(((ch) * 10 + 8 + w) << 9) + (lane << 3)], &wlds[b][(8 + w) << 9]); \
    }

    f32x4 acc[5][2];
#pragma unroll
    for (int a = 0; a < 5; ++a)
#pragma unroll
        for (int b = 0; b < 2; ++b) acc[a][b] = (f32x4)0.f;
    float ss0 = 0.f, ss1 = 0.f;

    // prologue: stage chunks 0 and 1 into both buffers (7/6 DMAs per wave each)
    XSTAGE(0, choff) WSTAGE(0, choff)
    XSTAGE(1, (1 + choff) & 15) WSTAGE(1, (1 + choff) & 15)

#pragma unroll 2
    for (int ch0 = 0; ch0 < 16; ++ch0) {
        const int cur = ch0 & 1;
        const int ch = (ch0 + choff) & 15;
        // counted wait: own current-chunk DMAs done; next chunk's stay in flight
        if (ch0 == 15) { asm volatile("s_waitcnt vmcnt(0)" ::: "memory"); }
        else if (w < 2) { asm volatile("s_waitcnt vmcnt(7)" ::: "memory"); }
        else            { asm volatile("s_waitcnt vmcnt(6)" ::: "memory"); }
        __builtin_amdgcn_s_barrier();          // all waves' cur data visible
        __builtin_amdgcn_sched_barrier(0);     // rule #18: no hoisting past the wait
        // ---- x fragments from LDS (one float2 feeds both l-tiles)
        float e0[8], e1[8];
#pragma unroll
        for (int j = 0; j < 8; ++j) {
            int c = agrp * 8 + j;
            float2 v = *reinterpret_cast<const float2*>(
                &xs[cur][(c >> 1) * XSEG + (c & 1) * 128 + w * 32 + 2 * arow]);
            e0[j] = v.x;     // l = lw0 + 2*arow     (tile 0)
            e1[j] = v.y;     // l = lw0 + 2*arow + 1 (tile 1)
        }
#pragma unroll
        for (int j = 0; j < 8; ++j) { ss0 += e0[j] * e0[j]; ss1 += e1[j] * e1[j]; }
        U4 bh[2], bl[2];
        bh[0].u.x = pack2(e0[0], e0[1]); bh[0].u.y = pack2(e0[2], e0[3]);
        bh[0].u.z = pack2(e0[4], e0[5]); bh[0].u.w = pack2(e0[6], e0[7]);
        bh[1].u.x = pack2(e1[0], e1[1]); bh[1].u.y = pack2(e1[2], e1[3]);
        bh[1].u.z = pack2(e1[4], e1[5]); bh[1].u.w = pack2(e1[6], e1[7]);
        float r0, r1, r2, r3;
        r0 = e0[0] - bfh_f(e0[0]); r1 = e0[1] - bfh_f(e0[1]);
        r2 = e0[2] - bfh_f(e0[2]); r3 = e0[3] - bfh_f(e0[3]);
        bl[0].u.x = pack2(r0, r1); bl[0].u.y = pack2(r2, r3);
        r0 = e0[4] - bfh_f(e0[4]); r1 = e0[5] - bfh_f(e0[5]);
        r2 = e0[6] - bfh_f(e0[6]); r3 = e0[7] - bfh_f(e0[7]);
        bl[0].u.z = pack2(r0, r1); bl[0].u.w = pack2(r2, r3);
        r0 = e1[0] - bfh_f(e1[0]); r1 = e1[1] - bfh_f(e1[1]);
        r2 = e1[2] - bfh_f(e1[2]); r3 = e1[3] - bfh_f(e1[3]);
        bl[1].u.x = pack2(r0, r1); bl[1].u.y = pack2(r2, r3);
        r0 = e1[4] - bfh_f(e1[4]); r1 = e1[5] - bfh_f(e1[5]);
        r2 = e1[6] - bfh_f(e1[6]); r3 = e1[7] - bfh_f(e1[7]);
        bl[1].u.z = pack2(r0, r1); bl[1].u.w = pack2(r2, r3);
        // ---- weight fragments from LDS (broadcast across waves)
        U4 ah[5], al[5];
#pragma unroll
        for (int kt = 0; kt < 5; ++kt) {
            ah[kt].u = *reinterpret_cast<const uint4*>(&wlds[cur][(kt << 9) + (lane << 3)]);
            al[kt].u = *reinterpret_cast<const uint4*>(&wlds[cur][((5 + kt) << 9) + (lane << 3)]);
        }
#pragma unroll
        for (int kt = 0; kt < 5; ++kt)
#pragma unroll
            for (int lt = 0; lt < 2; ++lt) {
                acc[kt][lt] = __builtin_amdgcn_mfma_f32_16x16x32_bf16(ah[kt].b, bh[lt].b, acc[kt][lt], 0, 0, 0);
                acc[kt][lt] = __builtin_amdgcn_mfma_f32_16x16x32_bf16(ah[kt].b, bl[lt].b, acc[kt][lt], 0, 0, 0);
                acc[kt][lt] = __builtin_amdgcn_mfma_f32_16x16x32_bf16(al[kt].b, bh[lt].b, acc[kt][lt], 0, 0, 0);
            }
        __builtin_amdgcn_s_barrier();          // all waves done reading buf cur
        if (ch0 < 14) {
            const int nx = (ch0 + 2 + choff) & 15;
            XSTAGE(cur, nx) WSTAGE(cur, nx)    // refill cur buffer, stays in flight
        }
    }

    ss0 += __shfl_xor(ss0, 16, 64); ss0 += __shfl_xor(ss0, 32, 64);
    ss1 += __shfl_xor(ss1, 16, 64); ss1 += __shfl_xor(ss1, 32, 64);
    float invc[2];
    invc[0] = 1.0f / fmaxf(sqrtf(ss0), 1e-12f);
    invc[1] = 1.0f / fmaxf(sqrtf(ss1), 1e-12f);

    float4 wbv[5];
#pragma unroll
    for (int kt = 0; kt < 5; ++kt)
        wbv[kt] = *reinterpret_cast<const float4*>(&wb[kt * 16 + agrp * 4]);

    float aval[5][2][4];
    float rs[2];
#pragma unroll
    for (int lt = 0; lt < 2; ++lt) {
        float m = -1e30f;
#pragma unroll
        for (int kt = 0; kt < 5; ++kt)
#pragma unroll
            for (int r = 0; r < 4; ++r) {
                float lg = acc[kt][lt][r] * invc[lt] + ((const float*)&wbv[kt])[r];
                aval[kt][lt][r] = lg;
                m = fmaxf(m, lg);
            }
        m = fmaxf(m, __shfl_xor(m, 16, 64));
        m = fmaxf(m, __shfl_xor(m, 32, 64));
        float s = 0.f;
#pragma unroll
        for (int kt = 0; kt < 5; ++kt)
#pragma unroll
            for (int r = 0; r < 4; ++r) {
                float e = __expf(aval[kt][lt][r] - m);
                aval[kt][lt][r] = e;
                s += e;
            }
        s += __shfl_xor(s, 16, 64);
        s += __shfl_xor(s, 32, 64);
        rs[lt] = 1.0f / s;
    }

#pragma unroll
    for (int kt = 0; kt < 4; ++kt)
#pragma unroll
        for (int r = 0; r < 4; ++r) {
            int k = kt * 16 + agrp * 4 + r;
            float s01 = 0.f;
#pragma unroll
            for (int lt = 0; lt < 2; ++lt) {
                float a = aval[kt][lt][r] * rs[lt];
                aval[kt][lt][r] = a;
                s01 += a;
            }
#pragma unroll
            for (int off = 8; off; off >>= 1) s01 += __shfl_xor(s01, off, 64);
            if ((lane & 15) == 0)
                asum_part[((n * 8 + lb) * 4 + w) * KK + k] = s01;
            // packed u32 stores: both adjacent l's in one word (dense 64 B segments)
            float ap0 = aval[kt][0][r] * invc[0];
            float ap1 = aval[kt][1][r] * invc[1];
            unsigned h0 = bfh(ap0), h1 = bfh(ap1);
            float q0 = ap0 - __uint_as_float(h0 << 16);
            float q1 = ap1 - __uint_as_float(h1 << 16);
            int widx = (n * KK + k) * (L_DIM / 2) + (lw0 >> 1) + arow;
            aPh32[widx] = h0 | (h1 << 16);
            aPl32[widx] = bfh(q0) | (bfh(q1) << 16);
        }
}

// ---------------- a_sum reduce ----------------
__global__ void k_asum(const float* __restrict__ part, float* __restrict__ a_sum)
{
    int id = blockIdx.x * 256 + threadIdx.x;  // 4096
    int n = id >> 6, k = id & 63;
    float s = 0.f;
#pragma unroll
    for (int p = 0; p < 32; ++p) s += part[(n * 32 + p) * KK + k];
    a_sum[id] = s;
}

// ---------------- Stage 2: vlad = a'x^T - a_sum*cent, fused rnpart, XCD swizzle ------
#define S2P 72   // LDS row pitch in shorts (144 B, 16B-aligned rows)
__global__ __launch_bounds__(256) void k_s2v(
    const float* __restrict__ x, const unsigned short* __restrict__ aPh,
    const unsigned short* __restrict__ aPl, const float* __restrict__ a_sum,
    const float* __restrict__ cent, float* __restrict__ vlad,
    float* __restrict__ rnpart)
{
    __shared__ unsigned short Ah[64 * S2P], Al[64 * S2P];   // aP chunk [k][l]
    __shared__ unsigned short Bh[64 * S2P], Bl[64 * S2P];   // x  chunk [c][l]
    __shared__ float rnbuf[4][64];

    const int flat = blockIdx.x;
    const int cq = flat >> 6;                               // 0..7
    const int n  = ((flat & 7) << 3) | ((flat >> 3) & 7);   // bijective, XCD-pinned
    const int t = threadIdx.x, lane = t & 63, w = t >> 6;
    const int arow = lane & 15, agrp = lane >> 4;

    f32x4 acc[4];
#pragma unroll
    for (int a = 0; a < 4; ++a) acc[a] = (f32x4)0.f;

    for (int step = 0; step < 16; ++step) {
        const int l0 = step * 64;
        __syncthreads();   // previous iter's reads done before restage
#pragma unroll
        for (int p = 0; p < 2; ++p) {
            int idx = p * 256 + t;          // 0..511 (512 uint4 = 4096 shorts)
            int k = idx >> 3;               // 8 uint4 per 64-short row
            int lc = (idx & 7) * 8;
            size_t g = (size_t)(n * KK + k) * L_DIM + l0 + lc;
            *reinterpret_cast<uint4*>(&Ah[k * S2P + lc]) = *reinterpret_cast<const uint4*>(&aPh[g]);
            *reinterpret_cast<uint4*>(&Al[k * S2P + lc]) = *reinterpret_cast<const uint4*>(&aPl[g]);
        }
#pragma unroll
        for (int p = 0; p < 4; ++p) {
            int idx = p * 256 + t;          // 0..1023 (1024 float4)
            int c = idx >> 4;               // 16 float4 per 64-float row
            int lc = (idx & 15) * 4;
            float4 v = *reinterpret_cast<const float4*>(
                &x[((size_t)n * C_DIM + cq * 64 + c) * L_DIM + l0 + lc]);
            uint2 hw, lw;
            hw.x = pack2(v.x, v.y); hw.y = pack2(v.z, v.w);
            float r0 = v.x - bfh_f(v.x), r1 = v.y - bfh_f(v.y);
            float r2 = v.z - bfh_f(v.z), r3 = v.w - bfh_f(v.w);
            lw.x = pack2(r0, r1); lw.y = pack2(r2, r3);
            *reinterpret_cast<uint2*>(&Bh[c * S2P + lc]) = hw;
            *reinterpret_cast<uint2*>(&Bl[c * S2P + lc]) = lw;
        }
        __syncthreads();
#pragma unroll
        for (int ks = 0; ks < 2; ++ks) {
            const int koff = ks * 32 + agrp * 8;
            U4 bh, bl;
            bh.u = *reinterpret_cast<const uint4*>(&Bh[(w * 16 + arow) * S2P + koff]);
            bl.u = *reinterpret_cast<const uint4*>(&Bl[(w * 16 + arow) * S2P + koff]);
#pragma unroll
            for (int kt = 0; kt < 4; ++kt) {
                U4 ah, al;
                ah.u = *reinterpret_cast<const uint4*>(&Ah[(kt * 16 + arow) * S2P + koff]);
                al.u = *reinterpret_cast<const uint4*>(&Al[(kt * 16 + arow) * S2P + koff]);
                acc[kt] = __builtin_amdgcn_mfma_f32_16x16x32_bf16(ah.b, bh.b, acc[kt], 0, 0, 0);
                acc[kt] = __builtin_amdgcn_mfma_f32_16x16x32_bf16(ah.b, bl.b, acc[kt], 0, 0, 0);
                acc[kt] = __builtin_amdgcn_mfma_f32_16x16x32_bf16(al.b, bh.b, acc[kt], 0, 0, 0);
            }
        }
    }
    // ---- fused epilogue: v = acc - a_sum*cent; store v; per-k sumsq partial
    const int c = cq * 64 + w * 16 + arow;
    float myrn[4][4];
#pragma unroll
    for (int kt = 0; kt < 4; ++kt)
#pragma unroll
        for (int r = 0; r < 4; ++r) {
            int k = kt * 16 + agrp * 4 + r;
            float as = a_sum[n * 64 + k];
            float cv = cent[k * C_DIM + c];
            float v = acc[kt][r] - as * cv;
            vlad[((size_t)n * KK + k) * C_DIM + c] = v;
            float sq = v * v;
            sq += __shfl_xor(sq, 1, 64);
            sq += __shfl_xor(sq, 2, 64);
            sq += __shfl_xor(sq, 4, 64);
            sq += __shfl_xor(sq, 8, 64);
            myrn[kt][r] = sq;               // valid at arow == 0
        }
    if (arow == 0) {
#pragma unroll
        for (int kt = 0; kt < 4; ++kt)
#pragma unroll
            for (int r = 0; r < 4; ++r)
                rnbuf[w][kt * 16 + agrp * 4 + r] = myrn[kt][r];
    }
    __syncthreads();
    if (t < 64) {
        float s = rnbuf[0][t] + rnbuf[1][t] + rnbuf[2][t] + rnbuf[3][t];
        rnpart[((size_t)n * 64 + t) * 8 + cq] = s;
    }
}

// ---------------- per-n scale from rnpart ----------------
__global__ void k_scale(const float* __restrict__ rnpart, float* __restrict__ scale)
{
    int n = blockIdx.x;
    int k = threadIdx.x;    // 64
    float s = 0.f;
#pragma unroll
    for (int q = 0; q < 8; ++q) s += rnpart[((size_t)n * 64 + k) * 8 + q];
    float nrm = sqrtf(s);
    float den = fmaxf(nrm, 1e-12f);
    float tk = nrm / den;
    float tot = tk * tk;
#pragma unroll
    for (int off = 32; off; off >>= 1) tot += __shfl_down(tot, off, 64);
    tot = __shfl(tot, 0, 64);
    float g = fmaxf(sqrtf(tot), 1e-12f);
    scale[n * 64 + k] = 1.0f / (den * g);
}

// ---------------- final output: v * scale ----------------
__global__ void k_out(const float* __restrict__ vlad, const float* __restrict__ scale,
                      float* __restrict__ out)
{
    int nk = blockIdx.x;
    int t = threadIdx.x;
    float sc = scale[nk];
    for (int c = t; c < C_DIM; c += 256)
        out[(size_t)nk * C_DIM + c] = vlad[(size_t)nk * C_DIM + c] * sc;
}

extern "C" void kernel_launch(void* const* d_in, const int* in_sizes, int n_in,
                              void* d_out, int out_size, void* d_ws, size_t ws_size,
                              hipStream_t stream)
{
    const float* x    = (const float*)d_in[0];
    const float* cent = (const float*)d_in[1];
    const float* cw   = (const float*)d_in[2];
    const float* cb   = (const float*)d_in[3];
    float* out = (float*)d_out;
    char* ws = (char*)d_ws;

    unsigned short* wp  = (unsigned short*)(ws + 0);                // 160 KB merged
    float*          wb  = (float*)(ws + 262144);                    // 320 B
    unsigned short* aPh = (unsigned short*)(ws + 524288);           // 8 MB
    unsigned short* aPl = (unsigned short*)(ws + 8912896);          // 8 MB
    float* asum_part    = (float*)(ws + 17301504);                  // 512 KB
    float* a_sum        = (float*)(ws + 17825792);                  // 16 KB
    float* vlad         = (float*)(ws + 18874368);                  // 8 MB
    float* rnpart       = (float*)(ws + 27262976);                  // 128 KB
    float* scale        = (float*)(ws + 27394048);                  // 16 KB

    k_prep<<<dim3(16, 5), 256, 0, stream>>>(cw, cb, wp, wb);
    k_s1<<<dim3(8, 64), 256, 0, stream>>>(x, wp, wb,
                                          (unsigned*)aPh, (unsigned*)aPl, asum_part);
    k_asum<<<16, 256, 0, stream>>>(asum_part, a_sum);
    k_s2v<<<512, 256, 0, stream>>>(x, aPh, aPl, a_sum, cent, vlad, rnpart);
    k_scale<<<64, 64, 0, stream>>>(rnpart, scale);
    k_out<<<4096, 256, 0, stream>>>(vlad, scale, out);
}

// Round 24
// 69.893 us; speedup vs baseline: 1.2189x; 1.0177x over previous
//
#include <hip/hip_runtime.h>
#include <hip/hip_bf16.h>

#define C_DIM 512
#define L_DIM 1024
#define KK 64
#define KG 65
#define KP 80   // padded k rows (5 tiles of 16)

using f32x4  = __attribute__((ext_vector_type(4))) float;
using bf16x8 = __attribute__((ext_vector_type(8))) short;

union U4 { uint4 u; bf16x8 b; };

__device__ __forceinline__ unsigned bfh(float x) { return __float_as_uint(x) >> 16; }
__device__ __forceinline__ float bfh_f(float x) { return __uint_as_float(__float_as_uint(x) & 0xFFFF0000u); }

// pack two fp32 -> word of 2 bf16 (truncation): low16 = a, high16 = b
__device__ __forceinline__ unsigned pack2(float a, float b) {
    return __builtin_amdgcn_perm(__float_as_uint(b), __float_as_uint(a), 0x07060302u);
}

// async global->LDS DMA, 16 B/lane (wave covers 1 KB: LDS dest = base + lane*16)
__device__ __forceinline__ void load_lds16(const void* g, void* l) {
    __builtin_amdgcn_global_load_lds(
        (const __attribute__((address_space(1))) void*)g,
        (__attribute__((address_space(3))) void*)l, 16, 0, 0);
}

// ---------------- prep: conv_w split bf16 hi/lo, MFMA fragment order, merged buffer --
__global__ void k_prep(const float* __restrict__ conv_w, const float* __restrict__ conv_b,
                       unsigned short* __restrict__ wp, float* __restrict__ wb)
{
    int ch = blockIdx.x;          // 0..15
    int kt = blockIdx.y;          // 0..4
    int t  = threadIdx.x;         // 0..255
    for (int p = 0; p < 2; ++p) {
        int idx = p * 256 + t;    // 0..511
        int lane = idx >> 3, j = idx & 7;
        int k = kt * 16 + (lane & 15);
        int c = ch * 32 + (lane >> 4) * 8 + j;
        float v = (k < KG) ? conv_w[k * C_DIM + c] : 0.f;
        unsigned h = bfh(v);
        float r = v - __uint_as_float(h << 16);
        wp[((ch * 10 + kt) << 9) + idx]     = (unsigned short)h;
        wp[((ch * 10 + 5 + kt) << 9) + idx] = (unsigned short)bfh(r);
    }
    if (ch == 0 && kt == 0 && t < KP) wb[t] = (t < KG) ? conv_b[t] : -1e30f;
}

// ---------------- Stage 1: fully DMA-staged, 2-chunk-deep COUNTED-vmcnt pipeline -----
// Grid (8 lb, 64 n), block 256 = 4 waves. Per chunk: x = 16 DMA segs (1 KB each,
// contiguous), weights = 10 DMA segs. Per-wave issue counts {7,7,6,6}; counted
// s_waitcnt vmcnt(own_next_count) + raw s_barrier keeps next chunk's 26 DMAs in
// flight across this chunk's compute (T3/T4 — never drain vmcnt(0) in the loop).
#define XSEG 260   // floats per 1 KB x-segment + 16 B pad
__global__ __launch_bounds__(256) void k_s1(
    const float* __restrict__ x, const unsigned short* __restrict__ wp,
    const float* __restrict__ wb,
    unsigned* __restrict__ aPh32, unsigned* __restrict__ aPl32,
    float* __restrict__ asum_part)
{
    __shared__ float xs[2][16 * XSEG];              // 2 x 16.25 KB
    __shared__ unsigned short wlds[2][10 << 9];     // 2 x 10 KB

    const int lb = blockIdx.x, n = blockIdx.y;
    const int t = threadIdx.x, lane = t & 63, w = t >> 6;
    const int arow = lane & 15;          // A/C row & B col within tile
    const int agrp = lane >> 4;          // k-slice group
    const int gl0 = lb * 128;            // block's global l base
    const int lw0 = gl0 + w * 32;        // wave's global l base
    const int choff = (lb + n) & 15;     // block-uniform chunk rotation

    const float* xbase = x + (size_t)n * C_DIM * L_DIM;

    // x: wave w stages segments s = w*4..w*4+3 (seg s = c-rows {ch*32+2s, +1})
#define XSTAGE(b, ch) { _Pragma("unroll") \
    for (int i = 0; i < 4; ++i) { \
        int s = w * 4 + i; \
        const float* src = &xbase[(size_t)((ch) * 32 + s * 2 + (lane >> 5)) * L_DIM \
                                  + gl0 + (lane & 31) * 4]; \
        load_lds16(src, &xs[b][s * XSEG]); \
    } }
    // weights: wave w stages segs {w, w+4}; waves 0,1 also {8,9}
#define WSTAGE(b, ch) { \
    load_lds16(&wp[(((ch) * 10 + w) << 9) + (lane << 3)], &wlds[b][w << 9]); \
    load_lds16(&wp[(((ch) * 10 + w + 4) << 9) + (lane << 3)], &wlds[b][(w + 4) << 9]); \
    if (w < 2) \
        load_lds16(&wp[(((ch) * 10 + 8 + w) << 9) + (lane << 3)], &wlds[b][(8 + w) << 9]); \
    }

    f32x4 acc[5][2];
#pragma unroll
    for (int a = 0; a < 5; ++a)
#pragma unroll
        for (int b = 0; b < 2; ++b) acc[a][b] = (f32x4)0.f;
    float ss0 = 0.f, ss1 = 0.f;

    // prologue: stage chunks 0 and 1 into both buffers (7/6 DMAs per wave each)
    XSTAGE(0, choff) WSTAGE(0, choff)
    XSTAGE(1, (1 + choff) & 15) WSTAGE(1, (1 + choff) & 15)

#pragma unroll 2
    for (int ch0 = 0; ch0 < 16; ++ch0) {
        const int cur = ch0 & 1;
        const int ch = (ch0 + choff) & 15;
        // counted wait: own current-chunk DMAs done; next chunk's stay in flight
        if (ch0 == 15) { asm volatile("s_waitcnt vmcnt(0)" ::: "memory"); }
        else if (w < 2) { asm volatile("s_waitcnt vmcnt(7)" ::: "memory"); }
        else            { asm volatile("s_waitcnt vmcnt(6)" ::: "memory"); }
        __builtin_amdgcn_s_barrier();          // all waves' cur data visible
        __builtin_amdgcn_sched_barrier(0);     // rule #18: no hoisting past the wait
        // ---- x fragments from LDS (one float2 feeds both l-tiles)
        float e0[8], e1[8];
#pragma unroll
        for (int j = 0; j < 8; ++j) {
            int c = agrp * 8 + j;
            float2 v = *reinterpret_cast<const float2*>(
                &xs[cur][(c >> 1) * XSEG + (c & 1) * 128 + w * 32 + 2 * arow]);
            e0[j] = v.x;     // l = lw0 + 2*arow     (tile 0)
            e1[j] = v.y;     // l = lw0 + 2*arow + 1 (tile 1)
        }
#pragma unroll
        for (int j = 0; j < 8; ++j) { ss0 += e0[j] * e0[j]; ss1 += e1[j] * e1[j]; }
        U4 bh[2], bl[2];
        bh[0].u.x = pack2(e0[0], e0[1]); bh[0].u.y = pack2(e0[2], e0[3]);
        bh[0].u.z = pack2(e0[4], e0[5]); bh[0].u.w = pack2(e0[6], e0[7]);
        bh[1].u.x = pack2(e1[0], e1[1]); bh[1].u.y = pack2(e1[2], e1[3]);
        bh[1].u.z = pack2(e1[4], e1[5]); bh[1].u.w = pack2(e1[6], e1[7]);
        float r0, r1, r2, r3;
        r0 = e0[0] - bfh_f(e0[0]); r1 = e0[1] - bfh_f(e0[1]);
        r2 = e0[2] - bfh_f(e0[2]); r3 = e0[3] - bfh_f(e0[3]);
        bl[0].u.x = pack2(r0, r1); bl[0].u.y = pack2(r2, r3);
        r0 = e0[4] - bfh_f(e0[4]); r1 = e0[5] - bfh_f(e0[5]);
        r2 = e0[6] - bfh_f(e0[6]); r3 = e0[7] - bfh_f(e0[7]);
        bl[0].u.z = pack2(r0, r1); bl[0].u.w = pack2(r2, r3);
        r0 = e1[0] - bfh_f(e1[0]); r1 = e1[1] - bfh_f(e1[1]);
        r2 = e1[2] - bfh_f(e1[2]); r3 = e1[3] - bfh_f(e1[3]);
        bl[1].u.x = pack2(r0, r1); bl[1].u.y = pack2(r2, r3);
        r0 = e1[4] - bfh_f(e1[4]); r1 = e1[5] - bfh_f(e1[5]);
        r2 = e1[6] - bfh_f(e1[6]); r3 = e1[7] - bfh_f(e1[7]);
        bl[1].u.z = pack2(r0, r1); bl[1].u.w = pack2(r2, r3);
        // ---- weight fragments from LDS (broadcast across waves)
        U4 ah[5], al[5];
#pragma unroll
        for (int kt = 0; kt < 5; ++kt) {
            ah[kt].u = *reinterpret_cast<const uint4*>(&wlds[cur][(kt << 9) + (lane << 3)]);
            al[kt].u = *reinterpret_cast<const uint4*>(&wlds[cur][((5 + kt) << 9) + (lane << 3)]);
        }
#pragma unroll
        for (int kt = 0; kt < 5; ++kt)
#pragma unroll
            for (int lt = 0; lt < 2; ++lt) {
                acc[kt][lt] = __builtin_amdgcn_mfma_f32_16x16x32_bf16(ah[kt].b, bh[lt].b, acc[kt][lt], 0, 0, 0);
                acc[kt][lt] = __builtin_amdgcn_mfma_f32_16x16x32_bf16(ah[kt].b, bl[lt].b, acc[kt][lt], 0, 0, 0);
                acc[kt][lt] = __builtin_amdgcn_mfma_f32_16x16x32_bf16(al[kt].b, bh[lt].b, acc[kt][lt], 0, 0, 0);
            }
        __builtin_amdgcn_s_barrier();          // all waves done reading buf cur
        if (ch0 < 14) {
            const int nx = (ch0 + 2 + choff) & 15;
            XSTAGE(cur, nx) WSTAGE(cur, nx)    // refill cur buffer, stays in flight
        }
    }

    ss0 += __shfl_xor(ss0, 16, 64); ss0 += __shfl_xor(ss0, 32, 64);
    ss1 += __shfl_xor(ss1, 16, 64); ss1 += __shfl_xor(ss1, 32, 64);
    float invc[2];
    invc[0] = 1.0f / fmaxf(sqrtf(ss0), 1e-12f);
    invc[1] = 1.0f / fmaxf(sqrtf(ss1), 1e-12f);

    float4 wbv[5];
#pragma unroll
    for (int kt = 0; kt < 5; ++kt)
        wbv[kt] = *reinterpret_cast<const float4*>(&wb[kt * 16 + agrp * 4]);

    float aval[5][2][4];
    float rs[2];
#pragma unroll
    for (int lt = 0; lt < 2; ++lt) {
        float m = -1e30f;
#pragma unroll
        for (int kt = 0; kt < 5; ++kt)
#pragma unroll
            for (int r = 0; r < 4; ++r) {
                float lg = acc[kt][lt][r] * invc[lt] + ((const float*)&wbv[kt])[r];
                aval[kt][lt][r] = lg;
                m = fmaxf(m, lg);
            }
        m = fmaxf(m, __shfl_xor(m, 16, 64));
        m = fmaxf(m, __shfl_xor(m, 32, 64));
        float s = 0.f;
#pragma unroll
        for (int kt = 0; kt < 5; ++kt)
#pragma unroll
            for (int r = 0; r < 4; ++r) {
                float e = __expf(aval[kt][lt][r] - m);
                aval[kt][lt][r] = e;
                s += e;
            }
        s += __shfl_xor(s, 16, 64);
        s += __shfl_xor(s, 32, 64);
        rs[lt] = 1.0f / s;
    }

#pragma unroll
    for (int kt = 0; kt < 4; ++kt)
#pragma unroll
        for (int r = 0; r < 4; ++r) {
            int k = kt * 16 + agrp * 4 + r;
            float s01 = 0.f;
#pragma unroll
            for (int lt = 0; lt < 2; ++lt) {
                float a = aval[kt][lt][r] * rs[lt];
                aval[kt][lt][r] = a;
                s01 += a;
            }
#pragma unroll
            for (int off = 8; off; off >>= 1) s01 += __shfl_xor(s01, off, 64);
            if ((lane & 15) == 0)
                asum_part[((n * 8 + lb) * 4 + w) * KK + k] = s01;
            // packed u32 stores: both adjacent l's in one word (dense 64 B segments)
            float ap0 = aval[kt][0][r] * invc[0];
            float ap1 = aval[kt][1][r] * invc[1];
            unsigned h0 = bfh(ap0), h1 = bfh(ap1);
            float q0 = ap0 - __uint_as_float(h0 << 16);
            float q1 = ap1 - __uint_as_float(h1 << 16);
            int widx = (n * KK + k) * (L_DIM / 2) + (lw0 >> 1) + arow;
            aPh32[widx] = h0 | (h1 << 16);
            aPl32[widx] = bfh(q0) | (bfh(q1) << 16);
        }
}

// ---------------- Stage 2: vlad = a'x^T - a_sum*cent, fused a_sum + rnpart ----------
// a_sum recomputed per block from asum_part (L2-resident, 2K loads) -> k_asum
// launch eliminated.
#define S2P 72   // LDS row pitch in shorts (144 B, 16B-aligned rows)
__global__ __launch_bounds__(256) void k_s2v(
    const float* __restrict__ x, const unsigned short* __restrict__ aPh,
    const unsigned short* __restrict__ aPl, const float* __restrict__ asum_part,
    const float* __restrict__ cent, float* __restrict__ vlad,
    float* __restrict__ rnpart)
{
    __shared__ unsigned short Ah[64 * S2P], Al[64 * S2P];   // aP chunk [k][l]
    __shared__ unsigned short Bh[64 * S2P], Bl[64 * S2P];   // x  chunk [c][l]
    __shared__ float rnbuf[4][64];
    __shared__ float asum_lds[64];

    const int flat = blockIdx.x;
    const int cq = flat >> 6;                               // 0..7
    const int n  = ((flat & 7) << 3) | ((flat >> 3) & 7);   // bijective, XCD-pinned
    const int t = threadIdx.x, lane = t & 63, w = t >> 6;
    const int arow = lane & 15, agrp = lane >> 4;

    // ---- fused a_sum: threads 0..63 reduce the 32 partials for their k
    if (t < 64) {
        float s = 0.f;
#pragma unroll
        for (int p = 0; p < 32; ++p) s += asum_part[(n * 32 + p) * KK + t];
        asum_lds[t] = s;
    }
    // visibility covered by the first step's __syncthreads below

    f32x4 acc[4];
#pragma unroll
    for (int a = 0; a < 4; ++a) acc[a] = (f32x4)0.f;

    for (int step = 0; step < 16; ++step) {
        const int l0 = step * 64;
        __syncthreads();   // previous iter's reads done before restage
#pragma unroll
        for (int p = 0; p < 2; ++p) {
            int idx = p * 256 + t;          // 0..511 (512 uint4 = 4096 shorts)
            int k = idx >> 3;               // 8 uint4 per 64-short row
            int lc = (idx & 7) * 8;
            size_t g = (size_t)(n * KK + k) * L_DIM + l0 + lc;
            *reinterpret_cast<uint4*>(&Ah[k * S2P + lc]) = *reinterpret_cast<const uint4*>(&aPh[g]);
            *reinterpret_cast<uint4*>(&Al[k * S2P + lc]) = *reinterpret_cast<const uint4*>(&aPl[g]);
        }
#pragma unroll
        for (int p = 0; p < 4; ++p) {
            int idx = p * 256 + t;          // 0..1023 (1024 float4)
            int c = idx >> 4;               // 16 float4 per 64-float row
            int lc = (idx & 15) * 4;
            float4 v = *reinterpret_cast<const float4*>(
                &x[((size_t)n * C_DIM + cq * 64 + c) * L_DIM + l0 + lc]);
            uint2 hw, lw;
            hw.x = pack2(v.x, v.y); hw.y = pack2(v.z, v.w);
            float r0 = v.x - bfh_f(v.x), r1 = v.y - bfh_f(v.y);
            float r2 = v.z - bfh_f(v.z), r3 = v.w - bfh_f(v.w);
            lw.x = pack2(r0, r1); lw.y = pack2(r2, r3);
            *reinterpret_cast<uint2*>(&Bh[c * S2P + lc]) = hw;
            *reinterpret_cast<uint2*>(&Bl[c * S2P + lc]) = lw;
        }
        __syncthreads();
#pragma unroll
        for (int ks = 0; ks < 2; ++ks) {
            const int koff = ks * 32 + agrp * 8;
            U4 bh, bl;
            bh.u = *reinterpret_cast<const uint4*>(&Bh[(w * 16 + arow) * S2P + koff]);
            bl.u = *reinterpret_cast<const uint4*>(&Bl[(w * 16 + arow) * S2P + koff]);
#pragma unroll
            for (int kt = 0; kt < 4; ++kt) {
                U4 ah, al;
                ah.u = *reinterpret_cast<const uint4*>(&Ah[(kt * 16 + arow) * S2P + koff]);
                al.u = *reinterpret_cast<const uint4*>(&Al[(kt * 16 + arow) * S2P + koff]);
                acc[kt] = __builtin_amdgcn_mfma_f32_16x16x32_bf16(ah.b, bh.b, acc[kt], 0, 0, 0);
                acc[kt] = __builtin_amdgcn_mfma_f32_16x16x32_bf16(ah.b, bl.b, acc[kt], 0, 0, 0);
                acc[kt] = __builtin_amdgcn_mfma_f32_16x16x32_bf16(al.b, bh.b, acc[kt], 0, 0, 0);
            }
        }
    }
    // ---- fused epilogue: v = acc - a_sum*cent; store v; per-k sumsq partial
    const int c = cq * 64 + w * 16 + arow;
    float myrn[4][4];
#pragma unroll
    for (int kt = 0; kt < 4; ++kt)
#pragma unroll
        for (int r = 0; r < 4; ++r) {
            int k = kt * 16 + agrp * 4 + r;
            float as = asum_lds[k];
            float cv = cent[k * C_DIM + c];
            float v = acc[kt][r] - as * cv;
            vlad[((size_t)n * KK + k) * C_DIM + c] = v;
            float sq = v * v;
            sq += __shfl_xor(sq, 1, 64);
            sq += __shfl_xor(sq, 2, 64);
            sq += __shfl_xor(sq, 4, 64);
            sq += __shfl_xor(sq, 8, 64);
            myrn[kt][r] = sq;               // valid at arow == 0
        }
    if (arow == 0) {
#pragma unroll
        for (int kt = 0; kt < 4; ++kt)
#pragma unroll
            for (int r = 0; r < 4; ++r)
                rnbuf[w][kt * 16 + agrp * 4 + r] = myrn[kt][r];
    }
    __syncthreads();
    if (t < 64) {
        float s = rnbuf[0][t] + rnbuf[1][t] + rnbuf[2][t] + rnbuf[3][t];
        rnpart[((size_t)n * 64 + t) * 8 + cq] = s;
    }
}

// ---------------- per-n scale from rnpart ----------------
__global__ void k_scale(const float* __restrict__ rnpart, float* __restrict__ scale)
{
    int n = blockIdx.x;
    int k = threadIdx.x;    // 64
    float s = 0.f;
#pragma unroll
    for (int q = 0; q < 8; ++q) s += rnpart[((size_t)n * 64 + k) * 8 + q];
    float nrm = sqrtf(s);
    float den = fmaxf(nrm, 1e-12f);
    float tk = nrm / den;
    float tot = tk * tk;
#pragma unroll
    for (int off = 32; off; off >>= 1) tot += __shfl_down(tot, off, 64);
    tot = __shfl(tot, 0, 64);
    float g = fmaxf(sqrtf(tot), 1e-12f);
    scale[n * 64 + k] = 1.0f / (den * g);
}

// ---------------- final output: v * scale ----------------
__global__ void k_out(const float* __restrict__ vlad, const float* __restrict__ scale,
                      float* __restrict__ out)
{
    int nk = blockIdx.x;
    int t = threadIdx.x;
    float sc = scale[nk];
    for (int c = t; c < C_DIM; c += 256)
        out[(size_t)nk * C_DIM + c] = vlad[(size_t)nk * C_DIM + c] * sc;
}

extern "C" void kernel_launch(void* const* d_in, const int* in_sizes, int n_in,
                              void* d_out, int out_size, void* d_ws, size_t ws_size,
                              hipStream_t stream)
{
    const float* x    = (const float*)d_in[0];
    const float* cent = (const float*)d_in[1];
    const float* cw   = (const float*)d_in[2];
    const float* cb   = (const float*)d_in[3];
    float* out = (float*)d_out;
    char* ws = (char*)d_ws;

    unsigned short* wp  = (unsigned short*)(ws + 0);                // 160 KB merged
    float*          wb  = (float*)(ws + 262144);                    // 320 B
    unsigned short* aPh = (unsigned short*)(ws + 524288);           // 8 MB
    unsigned short* aPl = (unsigned short*)(ws + 8912896);          // 8 MB
    float* asum_part    = (float*)(ws + 17301504);                  // 512 KB
    float* vlad         = (float*)(ws + 18874368);                  // 8 MB
    float* rnpart       = (float*)(ws + 27262976);                  // 128 KB
    float* scale        = (float*)(ws + 27394048);                  // 16 KB

    k_prep<<<dim3(16, 5), 256, 0, stream>>>(cw, cb, wp, wb);
    k_s1<<<dim3(8, 64), 256, 0, stream>>>(x, wp, wb,
                                          (unsigned*)aPh, (unsigned*)aPl, asum_part);
    k_s2v<<<512, 256, 0, stream>>>(x, aPh, aPl, asum_part, cent, vlad, rnpart);
    k_scale<<<64, 64, 0, stream>>>(rnpart, scale);
    k_out<<<4096, 256, 0, stream>>>(vlad, scale, out);
}

// Round 25
// 69.039 us; speedup vs baseline: 1.2340x; 1.0124x over previous
//
#include <hip/hip_runtime.h>
#include <hip/hip_bf16.h>

#define C_DIM 512
#define L_DIM 1024
#define KK 64
#define KG 65
#define KP 80   // padded k rows (5 tiles of 16)

using f32x4  = __attribute__((ext_vector_type(4))) float;
using bf16x8 = __attribute__((ext_vector_type(8))) short;

union U4 { uint4 u; bf16x8 b; };

__device__ __forceinline__ unsigned bfh(float x) { return __float_as_uint(x) >> 16; }
__device__ __forceinline__ float bfh_f(float x) { return __uint_as_float(__float_as_uint(x) & 0xFFFF0000u); }

// pack two fp32 -> word of 2 bf16 (truncation): low16 = a, high16 = b
__device__ __forceinline__ unsigned pack2(float a, float b) {
    return __builtin_amdgcn_perm(__float_as_uint(b), __float_as_uint(a), 0x07060302u);
}

// async global->LDS DMA, 16 B/lane (wave covers 1 KB: LDS dest = base + lane*16)
__device__ __forceinline__ void load_lds16(const void* g, void* l) {
    __builtin_amdgcn_global_load_lds(
        (const __attribute__((address_space(1))) void*)g,
        (__attribute__((address_space(3))) void*)l, 16, 0, 0);
}

// ---------------- prep: conv_w split bf16 hi/lo, MFMA fragment order, merged buffer --
__global__ void k_prep(const float* __restrict__ conv_w, const float* __restrict__ conv_b,
                       unsigned short* __restrict__ wp, float* __restrict__ wb)
{
    int ch = blockIdx.x;          // 0..15
    int kt = blockIdx.y;          // 0..4
    int t  = threadIdx.x;         // 0..255
    for (int p = 0; p < 2; ++p) {
        int idx = p * 256 + t;    // 0..511
        int lane = idx >> 3, j = idx & 7;
        int k = kt * 16 + (lane & 15);
        int c = ch * 32 + (lane >> 4) * 8 + j;
        float v = (k < KG) ? conv_w[k * C_DIM + c] : 0.f;
        unsigned h = bfh(v);
        float r = v - __uint_as_float(h << 16);
        wp[((ch * 10 + kt) << 9) + idx]     = (unsigned short)h;
        wp[((ch * 10 + 5 + kt) << 9) + idx] = (unsigned short)bfh(r);
    }
    if (ch == 0 && kt == 0 && t < KP) wb[t] = (t < KG) ? conv_b[t] : -1e30f;
}

// ---------------- Stage 1: fully DMA-staged, 2-chunk-deep COUNTED-vmcnt pipeline -----
// Grid (8 lb, 64 n), block 256 = 4 waves. Per chunk: x = 16 DMA segs (1 KB each,
// contiguous), weights = 10 DMA segs. Per-wave issue counts {7,7,6,6}; counted
// s_waitcnt vmcnt(own_next_count) + raw s_barrier keeps next chunk's 26 DMAs in
// flight across this chunk's compute (T3/T4 — never drain vmcnt(0) in the loop).
#define XSEG 260   // floats per 1 KB x-segment + 16 B pad
__global__ __launch_bounds__(256) void k_s1(
    const float* __restrict__ x, const unsigned short* __restrict__ wp,
    const float* __restrict__ wb,
    unsigned* __restrict__ aPh32, unsigned* __restrict__ aPl32,
    float* __restrict__ asum_part)
{
    __shared__ float xs[2][16 * XSEG];              // 2 x 16.25 KB
    __shared__ unsigned short wlds[2][10 << 9];     // 2 x 10 KB

    const int lb = blockIdx.x, n = blockIdx.y;
    const int t = threadIdx.x, lane = t & 63, w = t >> 6;
    const int arow = lane & 15;          // A/C row & B col within tile
    const int agrp = lane >> 4;          // k-slice group
    const int gl0 = lb * 128;            // block's global l base
    const int lw0 = gl0 + w * 32;        // wave's global l base
    const int choff = (lb + n) & 15;     // block-uniform chunk rotation

    const float* xbase = x + (size_t)n * C_DIM * L_DIM;

    // x: wave w stages segments s = w*4..w*4+3 (seg s = c-rows {ch*32+2s, +1})
#define XSTAGE(b, ch) { _Pragma("unroll") \
    for (int i = 0; i < 4; ++i) { \
        int s = w * 4 + i; \
        const float* src = &xbase[(size_t)((ch) * 32 + s * 2 + (lane >> 5)) * L_DIM \
                                  + gl0 + (lane & 31) * 4]; \
        load_lds16(src, &xs[b][s * XSEG]); \
    } }
    // weights: wave w stages segs {w, w+4}; waves 0,1 also {8,9}
#define WSTAGE(b, ch) { \
    load_lds16(&wp[(((ch) * 10 + w) << 9) + (lane << 3)], &wlds[b][w << 9]); \
    load_lds16(&wp[(((ch) * 10 + w + 4) << 9) + (lane << 3)], &wlds[b][(w + 4) << 9]); \
    if (w < 2) \
        load_lds16(&wp[(((ch) * 10 + 8 + w) << 9) + (lane << 3)], &wlds[b][(8 + w) << 9]); \
    }

    f32x4 acc[5][2];
#pragma unroll
    for (int a = 0; a < 5; ++a)
#pragma unroll
        for (int b = 0; b < 2; ++b) acc[a][b] = (f32x4)0.f;
    float ss0 = 0.f, ss1 = 0.f;

    // prologue: stage chunks 0 and 1 into both buffers (7/6 DMAs per wave each)
    XSTAGE(0, choff) WSTAGE(0, choff)
    XSTAGE(1, (1 + choff) & 15) WSTAGE(1, (1 + choff) & 15)

#pragma unroll 2
    for (int ch0 = 0; ch0 < 16; ++ch0) {
        const int cur = ch0 & 1;
        const int ch = (ch0 + choff) & 15;
        // counted wait: own current-chunk DMAs done; next chunk's stay in flight
        if (ch0 == 15) { asm volatile("s_waitcnt vmcnt(0)" ::: "memory"); }
        else if (w < 2) { asm volatile("s_waitcnt vmcnt(7)" ::: "memory"); }
        else            { asm volatile("s_waitcnt vmcnt(6)" ::: "memory"); }
        __builtin_amdgcn_s_barrier();          // all waves' cur data visible
        __builtin_amdgcn_sched_barrier(0);     // rule #18: no hoisting past the wait
        // ---- x fragments from LDS (one float2 feeds both l-tiles)
        float e0[8], e1[8];
#pragma unroll
        for (int j = 0; j < 8; ++j) {
            int c = agrp * 8 + j;
            float2 v = *reinterpret_cast<const float2*>(
                &xs[cur][(c >> 1) * XSEG + (c & 1) * 128 + w * 32 + 2 * arow]);
            e0[j] = v.x;     // l = lw0 + 2*arow     (tile 0)
            e1[j] = v.y;     // l = lw0 + 2*arow + 1 (tile 1)
        }
#pragma unroll
        for (int j = 0; j < 8; ++j) { ss0 += e0[j] * e0[j]; ss1 += e1[j] * e1[j]; }
        U4 bh[2], bl[2];
        bh[0].u.x = pack2(e0[0], e0[1]); bh[0].u.y = pack2(e0[2], e0[3]);
        bh[0].u.z = pack2(e0[4], e0[5]); bh[0].u.w = pack2(e0[6], e0[7]);
        bh[1].u.x = pack2(e1[0], e1[1]); bh[1].u.y = pack2(e1[2], e1[3]);
        bh[1].u.z = pack2(e1[4], e1[5]); bh[1].u.w = pack2(e1[6], e1[7]);
        float r0, r1, r2, r3;
        r0 = e0[0] - bfh_f(e0[0]); r1 = e0[1] - bfh_f(e0[1]);
        r2 = e0[2] - bfh_f(e0[2]); r3 = e0[3] - bfh_f(e0[3]);
        bl[0].u.x = pack2(r0, r1); bl[0].u.y = pack2(r2, r3);
        r0 = e0[4] - bfh_f(e0[4]); r1 = e0[5] - bfh_f(e0[5]);
        r2 = e0[6] - bfh_f(e0[6]); r3 = e0[7] - bfh_f(e0[7]);
        bl[0].u.z = pack2(r0, r1); bl[0].u.w = pack2(r2, r3);
        r0 = e1[0] - bfh_f(e1[0]); r1 = e1[1] - bfh_f(e1[1]);
        r2 = e1[2] - bfh_f(e1[2]); r3 = e1[3] - bfh_f(e1[3]);
        bl[1].u.x = pack2(r0, r1); bl[1].u.y = pack2(r2, r3);
        r0 = e1[4] - bfh_f(e1[4]); r1 = e1[5] - bfh_f(e1[5]);
        r2 = e1[6] - bfh_f(e1[6]); r3 = e1[7] - bfh_f(e1[7]);
        bl[1].u.z = pack2(r0, r1); bl[1].u.w = pack2(r2, r3);
        // ---- weight fragments from LDS (broadcast across waves)
        U4 ah[5], al[5];
#pragma unroll
        for (int kt = 0; kt < 5; ++kt) {
            ah[kt].u = *reinterpret_cast<const uint4*>(&wlds[cur][(kt << 9) + (lane << 3)]);
            al[kt].u = *reinterpret_cast<const uint4*>(&wlds[cur][((5 + kt) << 9) + (lane << 3)]);
        }
#pragma unroll
        for (int kt = 0; kt < 5; ++kt)
#pragma unroll
            for (int lt = 0; lt < 2; ++lt) {
                acc[kt][lt] = __builtin_amdgcn_mfma_f32_16x16x32_bf16(ah[kt].b, bh[lt].b, acc[kt][lt], 0, 0, 0);
                acc[kt][lt] = __builtin_amdgcn_mfma_f32_16x16x32_bf16(ah[kt].b, bl[lt].b, acc[kt][lt], 0, 0, 0);
                acc[kt][lt] = __builtin_amdgcn_mfma_f32_16x16x32_bf16(al[kt].b, bh[lt].b, acc[kt][lt], 0, 0, 0);
            }
        __builtin_amdgcn_s_barrier();          // all waves done reading buf cur
        if (ch0 < 14) {
            const int nx = (ch0 + 2 + choff) & 15;
            XSTAGE(cur, nx) WSTAGE(cur, nx)    // refill cur buffer, stays in flight
        }
    }

    ss0 += __shfl_xor(ss0, 16, 64); ss0 += __shfl_xor(ss0, 32, 64);
    ss1 += __shfl_xor(ss1, 16, 64); ss1 += __shfl_xor(ss1, 32, 64);
    float invc[2];
    invc[0] = 1.0f / fmaxf(sqrtf(ss0), 1e-12f);
    invc[1] = 1.0f / fmaxf(sqrtf(ss1), 1e-12f);

    float4 wbv[5];
#pragma unroll
    for (int kt = 0; kt < 5; ++kt)
        wbv[kt] = *reinterpret_cast<const float4*>(&wb[kt * 16 + agrp * 4]);

    float aval[5][2][4];
    float rs[2];
#pragma unroll
    for (int lt = 0; lt < 2; ++lt) {
        float m = -1e30f;
#pragma unroll
        for (int kt = 0; kt < 5; ++kt)
#pragma unroll
            for (int r = 0; r < 4; ++r) {
                float lg = acc[kt][lt][r] * invc[lt] + ((const float*)&wbv[kt])[r];
                aval[kt][lt][r] = lg;
                m = fmaxf(m, lg);
            }
        m = fmaxf(m, __shfl_xor(m, 16, 64));
        m = fmaxf(m, __shfl_xor(m, 32, 64));
        float s = 0.f;
#pragma unroll
        for (int kt = 0; kt < 5; ++kt)
#pragma unroll
            for (int r = 0; r < 4; ++r) {
                float e = __expf(aval[kt][lt][r] - m);
                aval[kt][lt][r] = e;
                s += e;
            }
        s += __shfl_xor(s, 16, 64);
        s += __shfl_xor(s, 32, 64);
        rs[lt] = 1.0f / s;
    }

#pragma unroll
    for (int kt = 0; kt < 4; ++kt)
#pragma unroll
        for (int r = 0; r < 4; ++r) {
            int k = kt * 16 + agrp * 4 + r;
            float s01 = 0.f;
#pragma unroll
            for (int lt = 0; lt < 2; ++lt) {
                float a = aval[kt][lt][r] * rs[lt];
                aval[kt][lt][r] = a;
                s01 += a;
            }
#pragma unroll
            for (int off = 8; off; off >>= 1) s01 += __shfl_xor(s01, off, 64);
            if ((lane & 15) == 0)
                asum_part[((n * 8 + lb) * 4 + w) * KK + k] = s01;
            // packed u32 stores: both adjacent l's in one word (dense 64 B segments)
            float ap0 = aval[kt][0][r] * invc[0];
            float ap1 = aval[kt][1][r] * invc[1];
            unsigned h0 = bfh(ap0), h1 = bfh(ap1);
            float q0 = ap0 - __uint_as_float(h0 << 16);
            float q1 = ap1 - __uint_as_float(h1 << 16);
            int widx = (n * KK + k) * (L_DIM / 2) + (lw0 >> 1) + arow;
            aPh32[widx] = h0 | (h1 << 16);
            aPl32[widx] = bfh(q0) | (bfh(q1) << 16);
        }
}

// ---------------- Stage 2: vlad = a'x^T - a_sum*cent, fused a_sum + rnpart ----------
#define S2P 72   // LDS row pitch in shorts (144 B, 16B-aligned rows)
__global__ __launch_bounds__(256) void k_s2v(
    const float* __restrict__ x, const unsigned short* __restrict__ aPh,
    const unsigned short* __restrict__ aPl, const float* __restrict__ asum_part,
    const float* __restrict__ cent, float* __restrict__ vlad,
    float* __restrict__ rnpart)
{
    __shared__ unsigned short Ah[64 * S2P], Al[64 * S2P];   // aP chunk [k][l]
    __shared__ unsigned short Bh[64 * S2P], Bl[64 * S2P];   // x  chunk [c][l]
    __shared__ float rnbuf[4][64];
    __shared__ float asum_lds[64];

    const int flat = blockIdx.x;
    const int cq = flat >> 6;                               // 0..7
    const int n  = ((flat & 7) << 3) | ((flat >> 3) & 7);   // bijective, XCD-pinned
    const int t = threadIdx.x, lane = t & 63, w = t >> 6;
    const int arow = lane & 15, agrp = lane >> 4;

    // ---- fused a_sum: threads 0..63 reduce the 32 partials for their k
    if (t < 64) {
        float s = 0.f;
#pragma unroll
        for (int p = 0; p < 32; ++p) s += asum_part[(n * 32 + p) * KK + t];
        asum_lds[t] = s;
    }
    // visibility covered by the first step's __syncthreads below

    f32x4 acc[4];
#pragma unroll
    for (int a = 0; a < 4; ++a) acc[a] = (f32x4)0.f;

    for (int step = 0; step < 16; ++step) {
        const int l0 = step * 64;
        __syncthreads();   // previous iter's reads done before restage
#pragma unroll
        for (int p = 0; p < 2; ++p) {
            int idx = p * 256 + t;          // 0..511 (512 uint4 = 4096 shorts)
            int k = idx >> 3;               // 8 uint4 per 64-short row
            int lc = (idx & 7) * 8;
            size_t g = (size_t)(n * KK + k) * L_DIM + l0 + lc;
            *reinterpret_cast<uint4*>(&Ah[k * S2P + lc]) = *reinterpret_cast<const uint4*>(&aPh[g]);
            *reinterpret_cast<uint4*>(&Al[k * S2P + lc]) = *reinterpret_cast<const uint4*>(&aPl[g]);
        }
#pragma unroll
        for (int p = 0; p < 4; ++p) {
            int idx = p * 256 + t;          // 0..1023 (1024 float4)
            int c = idx >> 4;               // 16 float4 per 64-float row
            int lc = (idx & 15) * 4;
            float4 v = *reinterpret_cast<const float4*>(
                &x[((size_t)n * C_DIM + cq * 64 + c) * L_DIM + l0 + lc]);
            uint2 hw, lw;
            hw.x = pack2(v.x, v.y); hw.y = pack2(v.z, v.w);
            float r0 = v.x - bfh_f(v.x), r1 = v.y - bfh_f(v.y);
            float r2 = v.z - bfh_f(v.z), r3 = v.w - bfh_f(v.w);
            lw.x = pack2(r0, r1); lw.y = pack2(r2, r3);
            *reinterpret_cast<uint2*>(&Bh[c * S2P + lc]) = hw;
            *reinterpret_cast<uint2*>(&Bl[c * S2P + lc]) = lw;
        }
        __syncthreads();
#pragma unroll
        for (int ks = 0; ks < 2; ++ks) {
            const int koff = ks * 32 + agrp * 8;
            U4 bh, bl;
            bh.u = *reinterpret_cast<const uint4*>(&Bh[(w * 16 + arow) * S2P + koff]);
            bl.u = *reinterpret_cast<const uint4*>(&Bl[(w * 16 + arow) * S2P + koff]);
#pragma unroll
            for (int kt = 0; kt < 4; ++kt) {
                U4 ah, al;
                ah.u = *reinterpret_cast<const uint4*>(&Ah[(kt * 16 + arow) * S2P + koff]);
                al.u = *reinterpret_cast<const uint4*>(&Al[(kt * 16 + arow) * S2P + koff]);
                acc[kt] = __builtin_amdgcn_mfma_f32_16x16x32_bf16(ah.b, bh.b, acc[kt], 0, 0, 0);
                acc[kt] = __builtin_amdgcn_mfma_f32_16x16x32_bf16(ah.b, bl.b, acc[kt], 0, 0, 0);
                acc[kt] = __builtin_amdgcn_mfma_f32_16x16x32_bf16(al.b, bh.b, acc[kt], 0, 0, 0);
            }
        }
    }
    // ---- fused epilogue: v = acc - a_sum*cent; store v; per-k sumsq partial
    const int c = cq * 64 + w * 16 + arow;
    float myrn[4][4];
#pragma unroll
    for (int kt = 0; kt < 4; ++kt)
#pragma unroll
        for (int r = 0; r < 4; ++r) {
            int k = kt * 16 + agrp * 4 + r;
            float as = asum_lds[k];
            float cv = cent[k * C_DIM + c];
            float v = acc[kt][r] - as * cv;
            vlad[((size_t)n * KK + k) * C_DIM + c] = v;
            float sq = v * v;
            sq += __shfl_xor(sq, 1, 64);
            sq += __shfl_xor(sq, 2, 64);
            sq += __shfl_xor(sq, 4, 64);
            sq += __shfl_xor(sq, 8, 64);
            myrn[kt][r] = sq;               // valid at arow == 0
        }
    if (arow == 0) {
#pragma unroll
        for (int kt = 0; kt < 4; ++kt)
#pragma unroll
            for (int r = 0; r < 4; ++r)
                rnbuf[w][kt * 16 + agrp * 4 + r] = myrn[kt][r];
    }
    __syncthreads();
    if (t < 64) {
        float s = rnbuf[0][t] + rnbuf[1][t] + rnbuf[2][t] + rnbuf[3][t];
        rnpart[((size_t)n * 64 + t) * 8 + cq] = s;
    }
}

// ---------------- final output: recompute scale per block from rnpart, apply --------
// k_scale launch eliminated: wave 0 reduces rnpart[n] (512 L2-resident floats),
// derives den_k for this block's k via lane shuffle and the per-n global norm.
__global__ __launch_bounds__(256) void k_out(
    const float* __restrict__ vlad, const float* __restrict__ rnpart,
    float* __restrict__ out)
{
    __shared__ float sc_lds;
    int nk = blockIdx.x;
    int n = nk >> 6, k = nk & 63;
    int t = threadIdx.x;
    if (t < 64) {
        float s = 0.f;
#pragma unroll
        for (int q = 0; q < 8; ++q) s += rnpart[((size_t)n * 64 + t) * 8 + q];
        float nrm = sqrtf(s);
        float den = fmaxf(nrm, 1e-12f);
        float tk = nrm / den;
        float tot = tk * tk;
#pragma unroll
        for (int off = 32; off; off >>= 1) tot += __shfl_down(tot, off, 64);
        tot = __shfl(tot, 0, 64);
        float g = fmaxf(sqrtf(tot), 1e-12f);
        float myden = __shfl(den, k, 64);
        if (t == 0) sc_lds = 1.0f / (myden * g);
    }
    __syncthreads();
    float sc = sc_lds;
    for (int c = t; c < C_DIM; c += 256)
        out[(size_t)nk * C_DIM + c] = vlad[(size_t)nk * C_DIM + c] * sc;
}

extern "C" void kernel_launch(void* const* d_in, const int* in_sizes, int n_in,
                              void* d_out, int out_size, void* d_ws, size_t ws_size,
                              hipStream_t stream)
{
    const float* x    = (const float*)d_in[0];
    const float* cent = (const float*)d_in[1];
    const float* cw   = (const float*)d_in[2];
    const float* cb   = (const float*)d_in[3];
    float* out = (float*)d_out;
    char* ws = (char*)d_ws;

    unsigned short* wp  = (unsigned short*)(ws + 0);                // 160 KB merged
    float*          wb  = (float*)(ws + 262144);                    // 320 B
    unsigned short* aPh = (unsigned short*)(ws + 524288);           // 8 MB
    unsigned short* aPl = (unsigned short*)(ws + 8912896);          // 8 MB
    float* asum_part    = (float*)(ws + 17301504);                  // 512 KB
    float* vlad         = (float*)(ws + 18874368);                  // 8 MB
    float* rnpart       = (float*)(ws + 27262976);                  // 128 KB

    k_prep<<<dim3(16, 5), 256, 0, stream>>>(cw, cb, wp, wb);
    k_s1<<<dim3(8, 64), 256, 0, stream>>>(x, wp, wb,
                                          (unsigned*)aPh, (unsigned*)aPl, asum_part);
    k_s2v<<<512, 256, 0, stream>>>(x, aPh, aPl, asum_part, cent, vlad, rnpart);
    k_out<<<4096, 256, 0, stream>>>(vlad, rnpart, out);
}